// Round 2
// baseline (845.275 us; speedup 1.0000x reference)
//
#include <hip/hip_runtime.h>
#include <hip/hip_bf16.h>
#include <math.h>

#define NH   8
#define NSEQ 4096
#define NB   2
#define HID  256
#define VD   32
#define RANK 409   // 0-indexed; percentile pos = 0.1*(4096-1) = 409.5 -> lerp(s[409],s[410],0.5)
#define NBIN 512
#define CAP  1024  // chunked select buffer (M ~ 410 for this data -> 1 chunk)
#define CCAP 512   // max candidates handled by O(c^2) rank path

// exclusive scan over 256 per-thread counts; returns base; total via ref
__device__ __forceinline__ unsigned block_scan_excl(unsigned c, int tid,
                                                    volatile unsigned* s4,
                                                    unsigned& total) {
  const int lane = tid & 63, w = tid >> 6;
  unsigned incl = c;
#pragma unroll
  for (int d = 1; d < 64; d <<= 1) {
    unsigned o = __shfl_up(incl, d, 64);
    if (lane >= d) incl += o;
  }
  __syncthreads();
  if (lane == 63) s4[w] = incl;
  __syncthreads();
  unsigned base = 0;
#pragma unroll
  for (int i = 0; i < 4; i++)
    if (i < w) base += s4[i];
  total = s4[0] + s4[1] + s4[2] + s4[3];
  return base + incl - c;
}

// ---------------- kernel A: value[h][n][b*32+k] = x @ weight; + scales ------

__global__ __launch_bounds__(256) void value_kernel(
    const float* __restrict__ x, const float* __restrict__ w,
    const float* __restrict__ r, float* __restrict__ value,
    float* __restrict__ scales) {
  const int tid = threadIdx.x;

  if (blockIdx.x == 0 && tid < NH) {
    double rv = (double)r[tid];
    const float c0 = (float)(0.25 * 3.141592653589793 * (1.0 - 1e-07));
    float s1 = (float)sin(rv);
    float t = c0 * (1.0f + s1);
    scales[tid] = (float)tan((double)t);
  }

  const int n0 = blockIdx.x * 8;
  __shared__ float sx[NB][8][HID];
#pragma unroll
  for (int i = 0; i < 16; i++) {
    int idx = i * 256 + tid;
    int b = idx >> 11;
    int rem = idx & 2047;
    int nn = rem >> 8;
    int j = rem & 255;
    sx[b][nn][j] = x[((size_t)b * NSEQ + n0 + nn) * HID + j];
  }
  __syncthreads();

  const int h = tid >> 5, k = tid & 31;
  float acc[NB][8];
#pragma unroll
  for (int b = 0; b < NB; b++)
#pragma unroll
    for (int nn = 0; nn < 8; nn++) acc[b][nn] = 0.f;

  const float* wp = w + (size_t)h * HID * VD + k;
  for (int j4 = 0; j4 < HID; j4 += 4) {
    float wv0 = wp[(size_t)(j4 + 0) * VD];
    float wv1 = wp[(size_t)(j4 + 1) * VD];
    float wv2 = wp[(size_t)(j4 + 2) * VD];
    float wv3 = wp[(size_t)(j4 + 3) * VD];
#pragma unroll
    for (int b = 0; b < NB; b++) {
#pragma unroll
      for (int nn = 0; nn < 8; nn++) {
        const float4 xv = *reinterpret_cast<const float4*>(&sx[b][nn][j4]);
        float a = acc[b][nn];
        a = fmaf(xv.x, wv0, a);
        a = fmaf(xv.y, wv1, a);
        a = fmaf(xv.z, wv2, a);
        a = fmaf(xv.w, wv3, a);
        acc[b][nn] = a;
      }
    }
  }
#pragma unroll
  for (int b = 0; b < NB; b++)
#pragma unroll
    for (int nn = 0; nn < 8; nn++)
      value[((size_t)h * NSEQ + n0 + nn) * (NB * VD) + b * VD + k] = acc[b][nn];
}

// ---------------- kernel B: per (h,q): percentile -> softmax -> gather ------

__global__ __launch_bounds__(256, 8) void attn_kernel(
    const float* __restrict__ m_dist, const float* __restrict__ value,
    const float* __restrict__ scales, float* __restrict__ out) {
  const int tid = threadIdx.x;
  const int lane = tid & 63;
  const int wv = tid >> 6;
  // XCD swizzle: 32768 blocks, 8 XCDs -> XCD x runs exactly head x (value table L2-resident)
  const int bid0 = blockIdx.x;
  const int bid = ((bid0 & 7) << 12) | (bid0 >> 3);
  const int h = bid >> 12;
  const int q = bid & (NSEQ - 1);

  __shared__ unsigned s_hist[NBIN];      // 2 KB
  __shared__ float2 s_wi[CAP + 32];      // 8.25 KB (select buffer; reused as candidate buf)
  __shared__ float s_out[4][64];         // 1 KB
  __shared__ unsigned s_scanA[4];
  __shared__ unsigned s_scanB[4];
  __shared__ float s_psum[4];
  __shared__ float s_redA[8];            // refine reduce: cmin[4], cmax[4]
  __shared__ unsigned s_redc[4];         // refine reduce: count
  __shared__ float s_redB[12];           // mgt[4], lmin[4], cle[4]
  __shared__ unsigned s_bcu[4];
  __shared__ float s_bcf[2];

  const float scale = scales[h];
  const size_t rowbase = ((size_t)(h * NSEQ + q)) * NSEQ;

  // ---- load row (thread owns n = 16*tid + i), scale, local min ----
  float v[16];
  {
    const float4* row4 = reinterpret_cast<const float4*>(m_dist + rowbase) + (size_t)tid * 4;
#pragma unroll
    for (int a = 0; a < 4; a++) {
      float4 t4 = row4[a];
      v[4 * a + 0] = t4.x * scale;
      v[4 * a + 1] = t4.y * scale;
      v[4 * a + 2] = t4.z * scale;
      v[4 * a + 3] = t4.w * scale;
    }
  }
  float lmin = v[0];
#pragma unroll
  for (int i = 1; i < 16; i++) lmin = fminf(lmin, v[i]);

  s_hist[tid] = 0u;
  s_hist[tid + 256] = 0u;
  __syncthreads();

  // ---- level-1 histogram (monotone binning => value partition) ----
  float curlo = 0.f;
  float curbs = (float)NBIN / scale;  // inv bin width; inf-safe (NaN->0 on cvt, clamped)
#pragma unroll
  for (int i = 0; i < 16; i++) {
    int b = (int)((v[i] - curlo) * curbs);
    b = b < 0 ? 0 : (b > NBIN - 1 ? NBIN - 1 : b);
    atomicAdd(&s_hist[b], 1u);
  }
  __syncthreads();

  // locate bin containing rank RANK
  {
    unsigned c2 = s_hist[2 * tid] + s_hist[2 * tid + 1];
    unsigned tot;
    unsigned base = block_scan_excl(c2, tid, s_scanA, tot);
    if (base <= (unsigned)RANK && (unsigned)RANK < base + c2) {
      unsigned h0 = s_hist[2 * tid];
      if ((unsigned)RANK < base + h0) { s_bcu[0] = 2u * tid; s_bcu[1] = (unsigned)RANK - base; }
      else { s_bcu[0] = 2u * tid + 1u; s_bcu[1] = (unsigned)RANK - base - h0; }
    }
    if (tid == 0) s_bcu[2] = 0u;
  }
  __syncthreads();
  unsigned tb = s_bcu[0];
  unsigned rr = s_bcu[1];

  unsigned mask = 0;
#pragma unroll
  for (int i = 0; i < 16; i++) {
    int b = (int)((v[i] - curlo) * curbs);
    b = b < 0 ? 0 : (b > NBIN - 1 ? NBIN - 1 : b);
    if ((unsigned)b == tb) mask |= (1u << i);
  }

  // ---- multi-level rank refinement (hot path exits at level 0) ----
  float v409;
  for (int level = 0;; level++) {
    float cmin = INFINITY, cmax = -INFINITY;
    int c = 0;
#pragma unroll
    for (int i = 0; i < 16; i++)
      if (mask & (1u << i)) {
        cmin = fminf(cmin, v[i]);
        cmax = fmaxf(cmax, v[i]);
        c++;
      }
#pragma unroll
    for (int d = 32; d; d >>= 1) {
      cmin = fminf(cmin, __shfl_down(cmin, d, 64));
      cmax = fmaxf(cmax, __shfl_down(cmax, d, 64));
      c += __shfl_down(c, d, 64);
    }
    if (lane == 0) { s_redA[wv] = cmin; s_redA[4 + wv] = cmax; s_redc[wv] = (unsigned)c; }
    __syncthreads();
    cmin = fminf(fminf(s_redA[0], s_redA[1]), fminf(s_redA[2], s_redA[3]));
    cmax = fmaxf(fmaxf(s_redA[4], s_redA[5]), fmaxf(s_redA[6], s_redA[7]));
    unsigned cT = s_redc[0] + s_redc[1] + s_redc[2] + s_redc[3];

    if (cmin == cmax) { v409 = cmin; break; }

    if (cT <= CCAP || level >= 7) {
      float* s_cand = (float*)s_wi;
      if (tid == 0) s_bcf[0] = cmin;  // safety default (unreachable rank-miss)
#pragma unroll
      for (int i = 0; i < 16; i++)
        if (mask & (1u << i)) {
          unsigned p = atomicAdd(&s_bcu[2], 1u);
          if (p < 2u * (CAP + 32)) s_cand[p] = v[i];
        }
      __syncthreads();
      unsigned cc = s_bcu[2];
      if (cc > 2u * (CAP + 32)) cc = 2u * (CAP + 32);
      for (unsigned j = tid; j < cc; j += 256) {
        float u = s_cand[j];
        unsigned less = 0, eq = 0;
        for (unsigned kk = 0; kk < cc; kk++) {
          float g = s_cand[kk];
          less += (g < u) ? 1u : 0u;
          eq += (g == u) ? 1u : 0u;
        }
        if (less <= rr && rr < less + eq) s_bcf[0] = u;  // winners write identical value
      }
      __syncthreads();
      v409 = s_bcf[0];
      break;
    }

    // refine into target bin (cold path)
    float wbin = 1.0f / curbs;
    curlo = curlo + (float)tb * wbin;
    curbs = curbs * (float)NBIN;
    s_hist[tid] = 0u;
    s_hist[tid + 256] = 0u;
    if (tid == 0) s_bcu[2] = 0u;
    __syncthreads();
#pragma unroll
    for (int i = 0; i < 16; i++)
      if (mask & (1u << i)) {
        int b = (int)((v[i] - curlo) * curbs);
        b = b < 0 ? 0 : (b > NBIN - 1 ? NBIN - 1 : b);
        atomicAdd(&s_hist[b], 1u);
      }
    __syncthreads();
    unsigned c2 = s_hist[2 * tid] + s_hist[2 * tid + 1];
    unsigned tot;
    unsigned base2 = block_scan_excl(c2, tid, s_scanA, tot);
    if (base2 <= rr && rr < base2 + c2) {
      unsigned h0 = s_hist[2 * tid];
      if (rr < base2 + h0) { s_bcu[0] = 2u * tid; s_bcu[1] = rr - base2; }
      else { s_bcu[0] = 2u * tid + 1u; s_bcu[1] = rr - base2 - h0; }
    }
    __syncthreads();
    tb = s_bcu[0];
    rr = s_bcu[1];
    unsigned nmask = 0;
#pragma unroll
    for (int i = 0; i < 16; i++)
      if (mask & (1u << i)) {
        int b = (int)((v[i] - curlo) * curbs);
        b = b < 0 ? 0 : (b > NBIN - 1 ? NBIN - 1 : b);
        if ((unsigned)b == tb) nmask |= (1u << i);
      }
    mask = nmask;
  }

  // ---- s[410]: count<=v409, min>v409, global min; one fused reduction ----
  int cle = 0;
  float mgt = INFINITY;
#pragma unroll
  for (int i = 0; i < 16; i++) {
    cle += (v[i] <= v409) ? 1 : 0;
    if (v[i] > v409) mgt = fminf(mgt, v[i]);
  }
#pragma unroll
  for (int d = 32; d; d >>= 1) {
    cle += __shfl_down(cle, d, 64);
    mgt = fminf(mgt, __shfl_down(mgt, d, 64));
    lmin = fminf(lmin, __shfl_down(lmin, d, 64));
  }
  if (lane == 0) {
    s_redB[wv] = mgt;
    s_redB[4 + wv] = lmin;
    s_redB[8 + wv] = (float)cle;
  }
  __syncthreads();
  float mgtT = fminf(fminf(s_redB[0], s_redB[1]), fminf(s_redB[2], s_redB[3]));
  float minT = fminf(fminf(s_redB[4], s_redB[5]), fminf(s_redB[6], s_redB[7]));
  int cleT = (int)(((s_redB[8] + s_redB[9]) + s_redB[10]) + s_redB[11]);

  float v410 = (cleT >= RANK + 2) ? v409 : mgtT;
  float thr = 0.5f * v409 + 0.5f * v410;  // frac = 0.5 exactly (jax lerp midpoint)

  // ---- select <= thr: fused scan (positions) + psum (denominator) ----
  unsigned cnt = 0;
  float psum = 0.f;
#pragma unroll
  for (int i = 0; i < 16; i++)
    if (v[i] <= thr) {
      cnt++;
      psum += __expf(minT - v[i]);
    }
  unsigned incl = cnt;
#pragma unroll
  for (int d = 1; d < 64; d <<= 1) {
    unsigned o = __shfl_up(incl, d, 64);
    if (lane >= d) incl += o;
  }
  float ps = psum;
#pragma unroll
  for (int d = 32; d; d >>= 1) ps += __shfl_down(ps, d, 64);
  if (lane == 63) s_scanB[wv] = incl;
  if (lane == 0) s_psum[wv] = ps;
  __syncthreads();
  unsigned base = incl - cnt;
#pragma unroll
  for (int w = 0; w < 4; w++)
    if (w < wv) base += s_scanB[w];
  unsigned M = s_scanB[0] + s_scanB[1] + s_scanB[2] + s_scanB[3];
  float denom = ((s_psum[0] + s_psum[1]) + s_psum[2]) + s_psum[3];
  float invd = 1.0f / denom;

  // ---- chunked gather (1 chunk for M<=1024), 4-deep pipelined loads ----
  const float* vp_lane = value + (size_t)h * (NSEQ * NB * VD) + lane;
  float acc = 0.f;
  for (unsigned c0 = 0; c0 < M; c0 += CAP) {
    unsigned len = M - c0;
    if (len > CAP) len = CAP;
    unsigned padded = (len + 31u) & ~31u;
    __syncthreads();  // prior readers of s_wi done
    if ((unsigned)tid < padded - len) s_wi[len + tid] = make_float2(0.f, __int_as_float(0));
    unsigned p = base;
#pragma unroll
    for (int i = 0; i < 16; i++)
      if (v[i] <= thr) {
        unsigned rel = p - c0;  // unsigned wrap -> skipped when p < c0
        if (rel < len) s_wi[rel] = make_float2(__expf(minT - v[i]), __int_as_float(tid * 16 + i));
        p++;
      }
    __syncthreads();
    for (unsigned t0 = 0; t0 < padded; t0 += 16) {
      unsigned j = t0 + (unsigned)wv;
      float2 e0 = s_wi[j];
      float2 e1 = s_wi[j + 4];
      float2 e2 = s_wi[j + 8];
      float2 e3 = s_wi[j + 12];
      float a0 = vp_lane[(size_t)__float_as_int(e0.y) * (NB * VD)];
      float a1 = vp_lane[(size_t)__float_as_int(e1.y) * (NB * VD)];
      float a2 = vp_lane[(size_t)__float_as_int(e2.y) * (NB * VD)];
      float a3 = vp_lane[(size_t)__float_as_int(e3.y) * (NB * VD)];
      acc = fmaf(e0.x, a0, acc);
      acc = fmaf(e1.x, a1, acc);
      acc = fmaf(e2.x, a2, acc);
      acc = fmaf(e3.x, a3, acc);
    }
  }
  s_out[wv][lane] = acc;
  __syncthreads();

  if (tid < 64) {
    float totv = ((s_out[0][tid] + s_out[1][tid]) + s_out[2][tid]) + s_out[3][tid];
    float xo = totv * invd;
    float x3 = xo * xo * xo;
    float inner = 0.7978845608028654f * (xo + 0.044715f * x3);
    float g = 0.5f * xo * (1.0f + tanhf(inner));
    int bb = tid >> 5, kk = tid & 31;
    out[((size_t)bb * NSEQ + q) * (NH * VD) + (size_t)h * VD + kk] = g;
  }
}

// ---------------- launch ----------------------------------------------------

extern "C" void kernel_launch(void* const* d_in, const int* in_sizes, int n_in,
                              void* d_out, int out_size, void* d_ws, size_t ws_size,
                              hipStream_t stream) {
  const float* m_dist = (const float*)d_in[0];
  const float* x = (const float*)d_in[1];
  const float* r = (const float*)d_in[2];
  const float* w = (const float*)d_in[3];
  float* out = (float*)d_out;

  float* value = (float*)d_ws;                          // NH*NSEQ*NB*VD floats = 8 MB
  float* scales = value + (size_t)NH * NSEQ * NB * VD;  // + 8 floats

  value_kernel<<<dim3(NSEQ / 8), dim3(256), 0, stream>>>(x, w, r, value, scales);
  attn_kernel<<<dim3(NH * NSEQ), dim3(256), 0, stream>>>(m_dist, value, scales, out);
}

// Round 4
// 453.924 us; speedup vs baseline: 1.8622x; 1.8622x over previous
//
#include <hip/hip_runtime.h>
#include <hip/hip_bf16.h>
#include <math.h>

#define NH   8
#define NSEQ 4096
#define NB   2
#define HID  256
#define VD   32
#define RANK 409   // 0-indexed; percentile pos = 0.1*(4096-1) = 409.5 -> lerp(s[409],s[410],0.5)
#define NBIN 512
#define CAP  1024  // chunked select buffer (M ~ 410 for this data -> 1 chunk)
#define CCAP 512   // max candidates handled by O(c^2) rank path

typedef float floatx4 __attribute__((ext_vector_type(4)));

// exclusive scan over 256 per-thread counts; returns base; total via ref
__device__ __forceinline__ unsigned block_scan_excl(unsigned c, int tid,
                                                    volatile unsigned* s4,
                                                    unsigned& total) {
  const int lane = tid & 63, w = tid >> 6;
  unsigned incl = c;
#pragma unroll
  for (int d = 1; d < 64; d <<= 1) {
    unsigned o = __shfl_up(incl, d, 64);
    if (lane >= d) incl += o;
  }
  __syncthreads();
  if (lane == 63) s4[w] = incl;
  __syncthreads();
  unsigned base = 0;
#pragma unroll
  for (int i = 0; i < 4; i++)
    if (i < w) base += s4[i];
  total = s4[0] + s4[1] + s4[2] + s4[3];
  return base + incl - c;
}

// ---------------- kernel A: value[h][n][b*32+k] = x @ weight; + scales ------

__global__ __launch_bounds__(256) void value_kernel(
    const float* __restrict__ x, const float* __restrict__ w,
    const float* __restrict__ r, float* __restrict__ value,
    float* __restrict__ scales) {
  const int tid = threadIdx.x;

  if (blockIdx.x == 0 && tid < NH) {
    double rv = (double)r[tid];
    const float c0 = (float)(0.25 * 3.141592653589793 * (1.0 - 1e-07));
    float s1 = (float)sin(rv);
    float t = c0 * (1.0f + s1);
    scales[tid] = (float)tan((double)t);
  }

  const int n0 = blockIdx.x * 8;
  __shared__ float sx[NB][8][HID];
#pragma unroll
  for (int i = 0; i < 16; i++) {
    int idx = i * 256 + tid;
    int b = idx >> 11;
    int rem = idx & 2047;
    int nn = rem >> 8;
    int j = rem & 255;
    sx[b][nn][j] = x[((size_t)b * NSEQ + n0 + nn) * HID + j];
  }
  __syncthreads();

  const int h = tid >> 5, k = tid & 31;
  float acc[NB][8];
#pragma unroll
  for (int b = 0; b < NB; b++)
#pragma unroll
    for (int nn = 0; nn < 8; nn++) acc[b][nn] = 0.f;

  const float* wp = w + (size_t)h * HID * VD + k;
  for (int j4 = 0; j4 < HID; j4 += 4) {
    float wv0 = wp[(size_t)(j4 + 0) * VD];
    float wv1 = wp[(size_t)(j4 + 1) * VD];
    float wv2 = wp[(size_t)(j4 + 2) * VD];
    float wv3 = wp[(size_t)(j4 + 3) * VD];
#pragma unroll
    for (int b = 0; b < NB; b++) {
#pragma unroll
      for (int nn = 0; nn < 8; nn++) {
        const float4 xv = *reinterpret_cast<const float4*>(&sx[b][nn][j4]);
        float a = acc[b][nn];
        a = fmaf(xv.x, wv0, a);
        a = fmaf(xv.y, wv1, a);
        a = fmaf(xv.z, wv2, a);
        a = fmaf(xv.w, wv3, a);
        acc[b][nn] = a;
      }
    }
  }
#pragma unroll
  for (int b = 0; b < NB; b++)
#pragma unroll
    for (int nn = 0; nn < 8; nn++)
      value[((size_t)h * NSEQ + n0 + nn) * (NB * VD) + b * VD + k] = acc[b][nn];
}

// ---------------- kernel B: per (h,q): percentile -> softmax -> gather ------

__global__ __launch_bounds__(256, 4) void attn_kernel(
    const float* __restrict__ m_dist, const float* __restrict__ value,
    const float* __restrict__ scales, float* __restrict__ out) {
  const int tid = threadIdx.x;
  const int lane = tid & 63;
  const int wv = tid >> 6;
  // XCD swizzle: 32768 blocks, 8 XCDs -> XCD x runs exactly head x (value table L2-resident)
  const int bid0 = blockIdx.x;
  const int bid = ((bid0 & 7) << 12) | (bid0 >> 3);
  const int h = bid >> 12;
  const int q = bid & (NSEQ - 1);

  __shared__ unsigned s_hist[NBIN];      // 2 KB
  __shared__ float2 s_wi[CAP + 32];      // 8.25 KB (select buffer; reused as candidate buf)
  __shared__ float s_out[4][64];         // 1 KB
  __shared__ unsigned s_scanA[4];
  __shared__ unsigned s_scanB[4];
  __shared__ float s_psum[4];
  __shared__ float s_redA[8];            // refine reduce: cmin[4], cmax[4]
  __shared__ unsigned s_redc[4];         // refine reduce: count
  __shared__ float s_redB[12];           // mgt[4], lmin[4], cle[4]
  __shared__ unsigned s_bcu[4];
  __shared__ float s_bcf[2];

  const float scale = scales[h];
  const size_t rowbase = ((size_t)(h * NSEQ + q)) * NSEQ;

  // ---- load row (thread owns n = 16*tid + i), scale, local min ----
  // non-temporal: m_dist is streamed exactly once; keep value table L2-resident
  float v[16];
  {
    const floatx4* row4 = reinterpret_cast<const floatx4*>(m_dist + rowbase) + (size_t)tid * 4;
#pragma unroll
    for (int a = 0; a < 4; a++) {
      floatx4 t4 = __builtin_nontemporal_load(&row4[a]);
      v[4 * a + 0] = t4.x * scale;
      v[4 * a + 1] = t4.y * scale;
      v[4 * a + 2] = t4.z * scale;
      v[4 * a + 3] = t4.w * scale;
    }
  }
  float lmin = v[0];
#pragma unroll
  for (int i = 1; i < 16; i++) lmin = fminf(lmin, v[i]);

  s_hist[tid] = 0u;
  s_hist[tid + 256] = 0u;
  __syncthreads();

  // ---- level-1 histogram (monotone binning => value partition) ----
  float curlo = 0.f;
  float curbs = (float)NBIN / scale;  // inv bin width; inf-safe (NaN->0 on cvt, clamped)
#pragma unroll
  for (int i = 0; i < 16; i++) {
    int b = (int)((v[i] - curlo) * curbs);
    b = b < 0 ? 0 : (b > NBIN - 1 ? NBIN - 1 : b);
    atomicAdd(&s_hist[b], 1u);
  }
  __syncthreads();

  // locate bin containing rank RANK
  {
    unsigned c2 = s_hist[2 * tid] + s_hist[2 * tid + 1];
    unsigned tot;
    unsigned base = block_scan_excl(c2, tid, s_scanA, tot);
    if (base <= (unsigned)RANK && (unsigned)RANK < base + c2) {
      unsigned h0 = s_hist[2 * tid];
      if ((unsigned)RANK < base + h0) { s_bcu[0] = 2u * tid; s_bcu[1] = (unsigned)RANK - base; }
      else { s_bcu[0] = 2u * tid + 1u; s_bcu[1] = (unsigned)RANK - base - h0; }
    }
    if (tid == 0) s_bcu[2] = 0u;
  }
  __syncthreads();
  unsigned tb = s_bcu[0];
  unsigned rr = s_bcu[1];

  unsigned mask = 0;
#pragma unroll
  for (int i = 0; i < 16; i++) {
    int b = (int)((v[i] - curlo) * curbs);
    b = b < 0 ? 0 : (b > NBIN - 1 ? NBIN - 1 : b);
    if ((unsigned)b == tb) mask |= (1u << i);
  }

  // ---- multi-level rank refinement (hot path exits at level 0) ----
  float v409;
  for (int level = 0;; level++) {
    float cmin = INFINITY, cmax = -INFINITY;
    int c = 0;
#pragma unroll
    for (int i = 0; i < 16; i++)
      if (mask & (1u << i)) {
        cmin = fminf(cmin, v[i]);
        cmax = fmaxf(cmax, v[i]);
        c++;
      }
#pragma unroll
    for (int d = 32; d; d >>= 1) {
      cmin = fminf(cmin, __shfl_down(cmin, d, 64));
      cmax = fmaxf(cmax, __shfl_down(cmax, d, 64));
      c += __shfl_down(c, d, 64);
    }
    if (lane == 0) { s_redA[wv] = cmin; s_redA[4 + wv] = cmax; s_redc[wv] = (unsigned)c; }
    __syncthreads();
    cmin = fminf(fminf(s_redA[0], s_redA[1]), fminf(s_redA[2], s_redA[3]));
    cmax = fmaxf(fmaxf(s_redA[4], s_redA[5]), fmaxf(s_redA[6], s_redA[7]));
    unsigned cT = s_redc[0] + s_redc[1] + s_redc[2] + s_redc[3];

    if (cmin == cmax) { v409 = cmin; break; }

    if (cT <= CCAP || level >= 7) {
      float* s_cand = (float*)s_wi;
      if (tid == 0) s_bcf[0] = cmin;  // safety default (unreachable rank-miss)
#pragma unroll
      for (int i = 0; i < 16; i++)
        if (mask & (1u << i)) {
          unsigned p = atomicAdd(&s_bcu[2], 1u);
          if (p < 2u * (CAP + 32)) s_cand[p] = v[i];
        }
      __syncthreads();
      unsigned cc = s_bcu[2];
      if (cc > 2u * (CAP + 32)) cc = 2u * (CAP + 32);
      for (unsigned j = tid; j < cc; j += 256) {
        float u = s_cand[j];
        unsigned less = 0, eq = 0;
        for (unsigned kk = 0; kk < cc; kk++) {
          float g = s_cand[kk];
          less += (g < u) ? 1u : 0u;
          eq += (g == u) ? 1u : 0u;
        }
        if (less <= rr && rr < less + eq) s_bcf[0] = u;  // winners write identical value
      }
      __syncthreads();
      v409 = s_bcf[0];
      break;
    }

    // refine into target bin (cold path)
    float wbin = 1.0f / curbs;
    curlo = curlo + (float)tb * wbin;
    curbs = curbs * (float)NBIN;
    s_hist[tid] = 0u;
    s_hist[tid + 256] = 0u;
    if (tid == 0) s_bcu[2] = 0u;
    __syncthreads();
#pragma unroll
    for (int i = 0; i < 16; i++)
      if (mask & (1u << i)) {
        int b = (int)((v[i] - curlo) * curbs);
        b = b < 0 ? 0 : (b > NBIN - 1 ? NBIN - 1 : b);
        atomicAdd(&s_hist[b], 1u);
      }
    __syncthreads();
    unsigned c2 = s_hist[2 * tid] + s_hist[2 * tid + 1];
    unsigned tot;
    unsigned base2 = block_scan_excl(c2, tid, s_scanA, tot);
    if (base2 <= rr && rr < base2 + c2) {
      unsigned h0 = s_hist[2 * tid];
      if (rr < base2 + h0) { s_bcu[0] = 2u * tid; s_bcu[1] = rr - base2; }
      else { s_bcu[0] = 2u * tid + 1u; s_bcu[1] = rr - base2 - h0; }
    }
    __syncthreads();
    tb = s_bcu[0];
    rr = s_bcu[1];
    unsigned nmask = 0;
#pragma unroll
    for (int i = 0; i < 16; i++)
      if (mask & (1u << i)) {
        int b = (int)((v[i] - curlo) * curbs);
        b = b < 0 ? 0 : (b > NBIN - 1 ? NBIN - 1 : b);
        if ((unsigned)b == tb) nmask |= (1u << i);
      }
    mask = nmask;
  }

  // ---- s[410]: count<=v409, min>v409, global min; one fused reduction ----
  int cle = 0;
  float mgt = INFINITY;
#pragma unroll
  for (int i = 0; i < 16; i++) {
    cle += (v[i] <= v409) ? 1 : 0;
    if (v[i] > v409) mgt = fminf(mgt, v[i]);
  }
#pragma unroll
  for (int d = 32; d; d >>= 1) {
    cle += __shfl_down(cle, d, 64);
    mgt = fminf(mgt, __shfl_down(mgt, d, 64));
    lmin = fminf(lmin, __shfl_down(lmin, d, 64));
  }
  if (lane == 0) {
    s_redB[wv] = mgt;
    s_redB[4 + wv] = lmin;
    s_redB[8 + wv] = (float)cle;
  }
  __syncthreads();
  float mgtT = fminf(fminf(s_redB[0], s_redB[1]), fminf(s_redB[2], s_redB[3]));
  float minT = fminf(fminf(s_redB[4], s_redB[5]), fminf(s_redB[6], s_redB[7]));
  int cleT = (int)(((s_redB[8] + s_redB[9]) + s_redB[10]) + s_redB[11]);

  float v410 = (cleT >= RANK + 2) ? v409 : mgtT;
  float thr = 0.5f * v409 + 0.5f * v410;  // frac = 0.5 exactly (jax lerp midpoint)

  // ---- select <= thr: scan for positions (exp computed once, in write pass) ----
  unsigned cnt = 0;
#pragma unroll
  for (int i = 0; i < 16; i++)
    if (v[i] <= thr) cnt++;
  unsigned incl = cnt;
#pragma unroll
  for (int d = 1; d < 64; d <<= 1) {
    unsigned o = __shfl_up(incl, d, 64);
    if (lane >= d) incl += o;
  }
  if (lane == 63) s_scanB[wv] = incl;
  __syncthreads();
  unsigned base = incl - cnt;
#pragma unroll
  for (int w = 0; w < 4; w++)
    if (w < wv) base += s_scanB[w];
  unsigned M = s_scanB[0] + s_scanB[1] + s_scanB[2] + s_scanB[3];

  // ---- chunked gather (1 chunk for M<=1024); psum accumulated in write pass ----
  const float* vp_lane = value + (size_t)h * (NSEQ * NB * VD) + lane;
  float acc = 0.f;
  float psum = 0.f;
  for (unsigned c0 = 0; c0 < M; c0 += CAP) {
    unsigned len = M - c0;
    if (len > CAP) len = CAP;
    unsigned padded = (len + 31u) & ~31u;
    __syncthreads();  // prior readers of s_wi done
    if ((unsigned)tid < padded - len) s_wi[len + tid] = make_float2(0.f, __int_as_float(0));
    unsigned p = base;
#pragma unroll
    for (int i = 0; i < 16; i++)
      if (v[i] <= thr) {
        unsigned rel = p - c0;  // unsigned wrap -> skipped when p < c0
        if (rel < len) {
          float pw = __expf(minT - v[i]);
          s_wi[rel] = make_float2(pw, __int_as_float(tid * 16 + i));
          psum += pw;  // each selected element contributes in exactly one chunk
        }
        p++;
      }
    __syncthreads();
    for (unsigned t0 = 0; t0 < padded; t0 += 32) {
      unsigned j = t0 + (unsigned)wv;
      float2 e0 = s_wi[j];
      float2 e1 = s_wi[j + 4];
      float2 e2 = s_wi[j + 8];
      float2 e3 = s_wi[j + 12];
      float2 e4 = s_wi[j + 16];
      float2 e5 = s_wi[j + 20];
      float2 e6 = s_wi[j + 24];
      float2 e7 = s_wi[j + 28];
      float a0 = vp_lane[(size_t)__float_as_int(e0.y) * (NB * VD)];
      float a1 = vp_lane[(size_t)__float_as_int(e1.y) * (NB * VD)];
      float a2 = vp_lane[(size_t)__float_as_int(e2.y) * (NB * VD)];
      float a3 = vp_lane[(size_t)__float_as_int(e3.y) * (NB * VD)];
      float a4 = vp_lane[(size_t)__float_as_int(e4.y) * (NB * VD)];
      float a5 = vp_lane[(size_t)__float_as_int(e5.y) * (NB * VD)];
      float a6 = vp_lane[(size_t)__float_as_int(e6.y) * (NB * VD)];
      float a7 = vp_lane[(size_t)__float_as_int(e7.y) * (NB * VD)];
      acc = fmaf(e0.x, a0, acc);
      acc = fmaf(e1.x, a1, acc);
      acc = fmaf(e2.x, a2, acc);
      acc = fmaf(e3.x, a3, acc);
      acc = fmaf(e4.x, a4, acc);
      acc = fmaf(e5.x, a5, acc);
      acc = fmaf(e6.x, a6, acc);
      acc = fmaf(e7.x, a7, acc);
    }
  }
  // denominator: reduce per-thread psum (order-fixed -> deterministic)
#pragma unroll
  for (int d = 32; d; d >>= 1) psum += __shfl_down(psum, d, 64);
  if (lane == 0) s_psum[wv] = psum;
  s_out[wv][lane] = acc;
  __syncthreads();

  if (tid < 64) {
    float denom = ((s_psum[0] + s_psum[1]) + s_psum[2]) + s_psum[3];
    float invd = 1.0f / denom;
    float totv = ((s_out[0][tid] + s_out[1][tid]) + s_out[2][tid]) + s_out[3][tid];
    float xo = totv * invd;
    float x3 = xo * xo * xo;
    float inner = 0.7978845608028654f * (xo + 0.044715f * x3);
    float g = 0.5f * xo * (1.0f + tanhf(inner));
    int bb = tid >> 5, kk = tid & 31;
    out[((size_t)bb * NSEQ + q) * (NH * VD) + (size_t)h * VD + kk] = g;
  }
}

// ---------------- launch ----------------------------------------------------

extern "C" void kernel_launch(void* const* d_in, const int* in_sizes, int n_in,
                              void* d_out, int out_size, void* d_ws, size_t ws_size,
                              hipStream_t stream) {
  const float* m_dist = (const float*)d_in[0];
  const float* x = (const float*)d_in[1];
  const float* r = (const float*)d_in[2];
  const float* w = (const float*)d_in[3];
  float* out = (float*)d_out;

  float* value = (float*)d_ws;                          // NH*NSEQ*NB*VD floats = 8 MB
  float* scales = value + (size_t)NH * NSEQ * NB * VD;  // + 8 floats

  value_kernel<<<dim3(NSEQ / 8), dim3(256), 0, stream>>>(x, w, r, value, scales);
  attn_kernel<<<dim3(NH * NSEQ), dim3(256), 0, stream>>>(m_dist, value, scales, out);
}

// Round 5
// 392.572 us; speedup vs baseline: 2.1532x; 1.1563x over previous
//
#include <hip/hip_runtime.h>
#include <hip/hip_bf16.h>
#include <math.h>

#define NH   8
#define NSEQ 4096
#define NB   2
#define HID  256
#define VD   32
#define RANK 409   // 0-indexed; percentile pos = 0.1*(4096-1) = 409.5 -> lerp(s[409],s[410],0.5)
#define NBIN 256
#define CAP  1024  // chunked select buffer (M ~ 410 for this data -> 1 chunk)
#define CCAP 1024  // max candidates handled by O(c^2) rank path

typedef float floatx4 __attribute__((ext_vector_type(4)));

// exclusive scan over 256 per-thread counts; returns base; total via ref
__device__ __forceinline__ unsigned block_scan_excl(unsigned c, int tid,
                                                    volatile unsigned* s4,
                                                    unsigned& total) {
  const int lane = tid & 63, w = tid >> 6;
  unsigned incl = c;
#pragma unroll
  for (int d = 1; d < 64; d <<= 1) {
    unsigned o = __shfl_up(incl, d, 64);
    if (lane >= d) incl += o;
  }
  __syncthreads();
  if (lane == 63) s4[w] = incl;
  __syncthreads();
  unsigned base = 0;
#pragma unroll
  for (int i = 0; i < 4; i++)
    if (i < w) base += s4[i];
  total = s4[0] + s4[1] + s4[2] + s4[3];
  return base + incl - c;
}

// ---------------- kernel A: value[h][n][b*32+k] = x @ weight; + scales ------

__global__ __launch_bounds__(256) void value_kernel(
    const float* __restrict__ x, const float* __restrict__ w,
    const float* __restrict__ r, float* __restrict__ value,
    float* __restrict__ scales) {
  const int tid = threadIdx.x;

  if (blockIdx.x == 0 && tid < NH) {
    double rv = (double)r[tid];
    const float c0 = (float)(0.25 * 3.141592653589793 * (1.0 - 1e-07));
    float s1 = (float)sin(rv);
    float t = c0 * (1.0f + s1);
    scales[tid] = (float)tan((double)t);
  }

  const int n0 = blockIdx.x * 8;
  __shared__ float sx[NB][8][HID];
#pragma unroll
  for (int i = 0; i < 16; i++) {
    int idx = i * 256 + tid;
    int b = idx >> 11;
    int rem = idx & 2047;
    int nn = rem >> 8;
    int j = rem & 255;
    sx[b][nn][j] = x[((size_t)b * NSEQ + n0 + nn) * HID + j];
  }
  __syncthreads();

  const int h = tid >> 5, k = tid & 31;
  float acc[NB][8];
#pragma unroll
  for (int b = 0; b < NB; b++)
#pragma unroll
    for (int nn = 0; nn < 8; nn++) acc[b][nn] = 0.f;

  const float* wp = w + (size_t)h * HID * VD + k;
  for (int j4 = 0; j4 < HID; j4 += 4) {
    float wv0 = wp[(size_t)(j4 + 0) * VD];
    float wv1 = wp[(size_t)(j4 + 1) * VD];
    float wv2 = wp[(size_t)(j4 + 2) * VD];
    float wv3 = wp[(size_t)(j4 + 3) * VD];
#pragma unroll
    for (int b = 0; b < NB; b++) {
#pragma unroll
      for (int nn = 0; nn < 8; nn++) {
        const float4 xv = *reinterpret_cast<const float4*>(&sx[b][nn][j4]);
        float a = acc[b][nn];
        a = fmaf(xv.x, wv0, a);
        a = fmaf(xv.y, wv1, a);
        a = fmaf(xv.z, wv2, a);
        a = fmaf(xv.w, wv3, a);
        acc[b][nn] = a;
      }
    }
  }
#pragma unroll
  for (int b = 0; b < NB; b++)
#pragma unroll
    for (int nn = 0; nn < 8; nn++)
      value[((size_t)h * NSEQ + n0 + nn) * (NB * VD) + b * VD + k] = acc[b][nn];
}

// ---------------- kernel B: per (h,q): percentile -> softmax -> gather ------

__global__ __launch_bounds__(256, 4) void attn_kernel(
    const float* __restrict__ m_dist, const float* __restrict__ value,
    const float* __restrict__ scales, float* __restrict__ out) {
  const int tid = threadIdx.x;
  const int lane = tid & 63;
  const int wv = tid >> 6;
  // XCD swizzle: 32768 blocks, 8 XCDs -> XCD x runs exactly head x (value table L2-resident)
  const int bid0 = blockIdx.x;
  const int bid = ((bid0 & 7) << 12) | (bid0 >> 3);
  const int h = bid >> 12;
  const int q = bid & (NSEQ - 1);

  __shared__ unsigned s_hist[NBIN];      // 1 KB
  __shared__ float2 s_wi[CAP + 64];      // 8.5 KB (select buffer; reused as candidate buf)
  __shared__ float s_out[16][64];        // 4 KB: [wave*4+slot][col]
  __shared__ unsigned s_scanA[4];
  __shared__ unsigned s_scanB[4];
  __shared__ float s_psum[4];
  __shared__ float s_redf[16];           // cmin[4], cmax[4], mgt[4], lmin[4]
  __shared__ unsigned s_redc[4];
  __shared__ unsigned s_bcu[4];
  __shared__ float s_bcf[2];

  const float scale = scales[h];
  const size_t rowbase = ((size_t)(h * NSEQ + q)) * NSEQ;

  // ---- load row (thread owns n = 16*tid + i), scale, local min ----
  float v[16];
  {
    const floatx4* row4 = reinterpret_cast<const floatx4*>(m_dist + rowbase) + (size_t)tid * 4;
#pragma unroll
    for (int a = 0; a < 4; a++) {
      floatx4 t4 = __builtin_nontemporal_load(&row4[a]);
      v[4 * a + 0] = t4.x * scale;
      v[4 * a + 1] = t4.y * scale;
      v[4 * a + 2] = t4.z * scale;
      v[4 * a + 3] = t4.w * scale;
    }
  }
  float lmin = v[0];
#pragma unroll
  for (int i = 1; i < 16; i++) lmin = fminf(lmin, v[i]);

  s_hist[tid] = 0u;  // NBIN == 256
  __syncthreads();

  // ---- level-0 histogram; bins kept in registers (computed ONCE) ----
  const float binscale = (float)NBIN / scale;  // inf/0-safe: cvt NaN->0, clamped
  int bins[16];
#pragma unroll
  for (int i = 0; i < 16; i++) {
    int b = (int)(v[i] * binscale);
    b = b < 0 ? 0 : (b > NBIN - 1 ? NBIN - 1 : b);
    bins[i] = b;
    atomicAdd(&s_hist[b], 1u);
  }
  __syncthreads();

  // ---- locate bin containing rank RANK (1 bin per thread) ----
  {
    unsigned c1 = s_hist[tid];
    unsigned tot;
    unsigned base = block_scan_excl(c1, tid, s_scanA, tot);
    if (base <= (unsigned)RANK && (unsigned)RANK < base + c1) {
      s_bcu[0] = (unsigned)tid;
      s_bcu[1] = (unsigned)RANK - base;
    }
    if (tid == 0) s_bcu[2] = 0u;
  }
  __syncthreads();
  unsigned tb = s_bcu[0];
  unsigned rr = s_bcu[1];

  // ---- mask of candidates + running min-above-bin (fused, uses reg bins) ----
  unsigned mask = 0;
  float mgt_run = INFINITY;  // min over elements strictly above current cand range
#pragma unroll
  for (int i = 0; i < 16; i++) {
    if ((unsigned)bins[i] == tb) mask |= (1u << i);
    else if ((unsigned)bins[i] > tb) mgt_run = fminf(mgt_run, v[i]);
  }

  float curlo = 0.f, curbs = binscale;  // cold-path refine state
  float v409, v410, minT;

  // ---- multi-level rank refinement (hot path exits at level 0) ----
  for (int level = 0;; level++) {
    // fused reduction: cmin, cmax, mgt_run, lmin, count
    float cmin = INFINITY, cmax = -INFINITY;
    int c = 0;
#pragma unroll
    for (int i = 0; i < 16; i++)
      if (mask & (1u << i)) {
        cmin = fminf(cmin, v[i]);
        cmax = fmaxf(cmax, v[i]);
        c++;
      }
    float mg = mgt_run, lm = lmin;
#pragma unroll
    for (int d = 32; d; d >>= 1) {
      cmin = fminf(cmin, __shfl_down(cmin, d, 64));
      cmax = fmaxf(cmax, __shfl_down(cmax, d, 64));
      mg = fminf(mg, __shfl_down(mg, d, 64));
      lm = fminf(lm, __shfl_down(lm, d, 64));
      c += __shfl_down(c, d, 64);
    }
    if (lane == 0) {
      s_redf[wv] = cmin;
      s_redf[4 + wv] = cmax;
      s_redf[8 + wv] = mg;
      s_redf[12 + wv] = lm;
      s_redc[wv] = (unsigned)c;
    }
    __syncthreads();
    cmin = fminf(fminf(s_redf[0], s_redf[1]), fminf(s_redf[2], s_redf[3]));
    cmax = fmaxf(fmaxf(s_redf[4], s_redf[5]), fmaxf(s_redf[6], s_redf[7]));
    float mgtT = fminf(fminf(s_redf[8], s_redf[9]), fminf(s_redf[10], s_redf[11]));
    minT = fminf(fminf(s_redf[12], s_redf[13]), fminf(s_redf[14], s_redf[15]));
    unsigned cT = s_redc[0] + s_redc[1] + s_redc[2] + s_redc[3];

    if (cmin == cmax) {  // all candidates identical
      v409 = cmin;
      v410 = (rr + 1u < cT) ? cmin : mgtT;
      break;
    }

    if (cT <= CCAP || level >= 7) {  // O(c^2) exact ranks rr and rr+1
      float* s_cand = (float*)s_wi;
      if (tid == 0) { s_bcf[0] = cmin; s_bcf[1] = mgtT; }  // defaults
#pragma unroll
      for (int i = 0; i < 16; i++)
        if (mask & (1u << i)) {
          unsigned p = atomicAdd(&s_bcu[2], 1u);
          if (p < 2u * (CAP + 64)) s_cand[p] = v[i];
        }
      __syncthreads();
      unsigned cc = s_bcu[2];
      if (cc > 2u * (CAP + 64)) cc = 2u * (CAP + 64);
      for (unsigned j = tid; j < cc; j += 256) {
        float u = s_cand[j];
        unsigned less = 0, eq = 0;
        for (unsigned kk = 0; kk < cc; kk++) {
          float g = s_cand[kk];
          less += (g < u) ? 1u : 0u;
          eq += (g == u) ? 1u : 0u;
        }
        if (less <= rr && rr < less + eq) s_bcf[0] = u;            // winners identical
        if (less <= rr + 1u && rr + 1u < less + eq) s_bcf[1] = u;  // rank rr+1 if in-set
      }
      __syncthreads();
      v409 = s_bcf[0];
      v410 = s_bcf[1];  // == mgtT when rank rr+1 lies above the candidate set
      break;
    }

    // ---- refine into target bin (cold path, recompute bins) ----
    float wbin = 1.0f / curbs;
    curlo = curlo + (float)tb * wbin;
    curbs = curbs * (float)NBIN;
    s_hist[tid] = 0u;
    if (tid == 0) s_bcu[2] = 0u;
    __syncthreads();
#pragma unroll
    for (int i = 0; i < 16; i++)
      if (mask & (1u << i)) {
        int b = (int)((v[i] - curlo) * curbs);
        b = b < 0 ? 0 : (b > NBIN - 1 ? NBIN - 1 : b);
        atomicAdd(&s_hist[b], 1u);
      }
    __syncthreads();
    {
      unsigned c1 = s_hist[tid];
      unsigned tot;
      unsigned b2 = block_scan_excl(c1, tid, s_scanA, tot);
      if (b2 <= rr && rr < b2 + c1) {
        s_bcu[0] = (unsigned)tid;
        s_bcu[1] = rr - b2;
      }
    }
    __syncthreads();
    tb = s_bcu[0];
    rr = s_bcu[1];
    unsigned nmask = 0;
#pragma unroll
    for (int i = 0; i < 16; i++)
      if (mask & (1u << i)) {
        int b = (int)((v[i] - curlo) * curbs);
        b = b < 0 ? 0 : (b > NBIN - 1 ? NBIN - 1 : b);
        if ((unsigned)b == tb) nmask |= (1u << i);
        else if ((unsigned)b > tb) mgt_run = fminf(mgt_run, v[i]);
      }
    mask = nmask;
  }

  float thr = 0.5f * v409 + 0.5f * v410;  // frac = 0.5 exactly (jax lerp midpoint)

  // ---- select <= thr: scan for positions ----
  unsigned cnt = 0;
#pragma unroll
  for (int i = 0; i < 16; i++)
    if (v[i] <= thr) cnt++;
  unsigned incl = cnt;
#pragma unroll
  for (int d = 1; d < 64; d <<= 1) {
    unsigned o = __shfl_up(incl, d, 64);
    if (lane >= d) incl += o;
  }
  if (lane == 63) s_scanB[wv] = incl;
  __syncthreads();
  unsigned base = incl - cnt;
#pragma unroll
  for (int w = 0; w < 4; w++)
    if (w < wv) base += s_scanB[w];
  unsigned M = s_scanB[0] + s_scanB[1] + s_scanB[2] + s_scanB[3];

  // ---- chunked gather: 16 lanes x float4 per row, 4 rows per wave-step ----
  const int slot4 = lane >> 4;  // entry slot within wave (0..3)
  const int cg = lane & 15;     // column group: floats 4*cg..4*cg+3
  const floatx4* vp4 = reinterpret_cast<const floatx4*>(value + (size_t)h * (NSEQ * NB * VD)) + cg;
  floatx4 acc4 = {0.f, 0.f, 0.f, 0.f};
  float psum = 0.f;
  for (unsigned c0 = 0; c0 < M; c0 += CAP) {
    unsigned len = M - c0;
    if (len > CAP) len = CAP;
    unsigned padded = (len + 63u) & ~63u;  // multiple of 64 entries (4 waves x 4 slots x 4 unroll)
    __syncthreads();                       // prior readers of s_wi done
    if ((unsigned)tid < padded - len) s_wi[len + tid] = make_float2(0.f, __int_as_float(0));
    unsigned p = base;
#pragma unroll
    for (int i = 0; i < 16; i++)
      if (v[i] <= thr) {
        unsigned rel = p - c0;  // unsigned wrap -> skipped when p < c0
        if (rel < len) {
          float pw = __expf(minT - v[i]);
          s_wi[rel] = make_float2(pw, __int_as_float(tid * 16 + i));
          psum += pw;  // each selected element contributes in exactly one chunk
        }
        p++;
      }
    __syncthreads();
    for (unsigned t0 = 0; t0 < padded; t0 += 64) {
      unsigned j = t0 + (unsigned)(wv * 4 + slot4);
      float2 e0 = s_wi[j];
      float2 e1 = s_wi[j + 16];
      float2 e2 = s_wi[j + 32];
      float2 e3 = s_wi[j + 48];
      floatx4 a0 = vp4[(size_t)__float_as_int(e0.y) * 16];
      floatx4 a1 = vp4[(size_t)__float_as_int(e1.y) * 16];
      floatx4 a2 = vp4[(size_t)__float_as_int(e2.y) * 16];
      floatx4 a3 = vp4[(size_t)__float_as_int(e3.y) * 16];
      acc4.x = fmaf(e0.x, a0.x, acc4.x);
      acc4.y = fmaf(e0.x, a0.y, acc4.y);
      acc4.z = fmaf(e0.x, a0.z, acc4.z);
      acc4.w = fmaf(e0.x, a0.w, acc4.w);
      acc4.x = fmaf(e1.x, a1.x, acc4.x);
      acc4.y = fmaf(e1.x, a1.y, acc4.y);
      acc4.z = fmaf(e1.x, a1.z, acc4.z);
      acc4.w = fmaf(e1.x, a1.w, acc4.w);
      acc4.x = fmaf(e2.x, a2.x, acc4.x);
      acc4.y = fmaf(e2.x, a2.y, acc4.y);
      acc4.z = fmaf(e2.x, a2.z, acc4.z);
      acc4.w = fmaf(e2.x, a2.w, acc4.w);
      acc4.x = fmaf(e3.x, a3.x, acc4.x);
      acc4.y = fmaf(e3.x, a3.y, acc4.y);
      acc4.z = fmaf(e3.x, a3.z, acc4.z);
      acc4.w = fmaf(e3.x, a3.w, acc4.w);
    }
  }
  // denominator: reduce per-thread psum (order-fixed -> deterministic)
#pragma unroll
  for (int d = 32; d; d >>= 1) psum += __shfl_down(psum, d, 64);
  if (lane == 0) s_psum[wv] = psum;
  *reinterpret_cast<floatx4*>(&s_out[wv * 4 + slot4][cg * 4]) = acc4;
  __syncthreads();

  if (tid < 64) {
    float denom = ((s_psum[0] + s_psum[1]) + s_psum[2]) + s_psum[3];
    float invd = 1.0f / denom;
    float totv = 0.f;
#pragma unroll
    for (int g = 0; g < 16; g++) totv += s_out[g][tid];
    float xo = totv * invd;
    float x3 = xo * xo * xo;
    float inner = 0.7978845608028654f * (xo + 0.044715f * x3);
    float g = 0.5f * xo * (1.0f + tanhf(inner));
    int bb = tid >> 5, kk = tid & 31;
    out[((size_t)bb * NSEQ + q) * (NH * VD) + (size_t)h * VD + kk] = g;
  }
}

// ---------------- launch ----------------------------------------------------

extern "C" void kernel_launch(void* const* d_in, const int* in_sizes, int n_in,
                              void* d_out, int out_size, void* d_ws, size_t ws_size,
                              hipStream_t stream) {
  const float* m_dist = (const float*)d_in[0];
  const float* x = (const float*)d_in[1];
  const float* r = (const float*)d_in[2];
  const float* w = (const float*)d_in[3];
  float* out = (float*)d_out;

  float* value = (float*)d_ws;                          // NH*NSEQ*NB*VD floats = 8 MB
  float* scales = value + (size_t)NH * NSEQ * NB * VD;  // + 8 floats

  value_kernel<<<dim3(NSEQ / 8), dim3(256), 0, stream>>>(x, w, r, value, scales);
  attn_kernel<<<dim3(NH * NSEQ), dim3(256), 0, stream>>>(m_dist, value, scales, out);
}